// Round 1
// baseline (1809.354 us; speedup 1.0000x reference)
//
#include <hip/hip_runtime.h>
#include <hip/hip_bf16.h>
#include <math.h>

#define B 8
#define HH 28
#define WDIM 28
#define PIX 784          // 28*28
#define M_TOT 6272       // B*PIX
#define NK 9
#define C1 256
#define HID 1024
#define K1 (C1*NK)       // 2304
#define K2 (HID*NK)      // 9216

// ---------------- offset(18)+mask(9) 3x3 conv, direct, LDS row staging ----
__global__ __launch_bounds__(768) void pconv_kernel(
    const float* __restrict__ x,   // [B][C][28][28]
    const float* __restrict__ w_p, // [18][C][3][3]
    const float* __restrict__ b_p, // [18]
    const float* __restrict__ w_m, // [9][C][3][3]
    const float* __restrict__ b_m, // [9]
    float* __restrict__ pm,        // [M][27]  (0..17 offset, 18..26 sigmoid mask)
    int C)
{
  __shared__ float xs[16][3][32];  // 16 ch x 3 rows x 30 padded cols (stride 32)
  int bh = blockIdx.x;
  int b = bh / HH, h = bh % HH;
  int t = threadIdx.x;
  int ch = t / WDIM, w = t % WDIM;          // valid when t < 756
  bool active = (t < 27 * WDIM);
  float acc = 0.f;
  const float* wbase = nullptr;
  if (active) {
    if (ch < 18) { acc = b_p[ch];      wbase = w_p + (size_t)ch * C * 9; }
    else         { acc = b_m[ch - 18]; wbase = w_m + (size_t)(ch - 18) * C * 9; }
  }
  for (int cc = 0; cc < C; cc += 16) {
    __syncthreads();
    for (int i = t; i < 16 * 3 * 30; i += 768) {
      int c = i / 90, rem = i % 90, r = rem / 30, wc = rem % 30;
      int hy = h + r - 1, wx = wc - 1;
      float v = 0.f;
      if (hy >= 0 && hy < HH && wx >= 0 && wx < WDIM)
        v = x[(((size_t)b * C + (cc + c)) * HH + hy) * WDIM + wx];
      xs[c][r][wc] = v;
    }
    __syncthreads();
    if (active) {
      const float* wp = wbase + (size_t)cc * 9;
      #pragma unroll 4
      for (int c = 0; c < 16; ++c) {
        const float* wr = wp + (size_t)c * 9;
        float s = 0.f;
        #pragma unroll
        for (int r = 0; r < 3; ++r)
          #pragma unroll
          for (int q = 0; q < 3; ++q)
            s += xs[c][r][w + q] * wr[r * 3 + q];
        acc += s;
      }
    }
  }
  if (active) {
    if (ch >= 18) acc = 1.f / (1.f + expf(-acc));
    pm[(size_t)(b * PIX + h * WDIM + w) * 27 + ch] = acc;
  }
}

// ---------------- per-(m,n) bilinear table: clamped corner offsets + gains --
__global__ __launch_bounds__(256) void mktab_kernel(
    const float* __restrict__ pm,
    int4* __restrict__ tabOff, float4* __restrict__ tabG)
{
  int i = blockIdx.x * 256 + threadIdx.x;
  if (i >= M_TOT * NK) return;
  int m = i / NK, n = i % NK;
  int pix = m % PIX;
  int hh = pix / WDIM, ww = pix % WDIM;
  const float* q = pm + (size_t)m * 27;
  float px = q[n]     + (float)(hh + 1) + (float)(n / 3 - 1);
  float py = q[9 + n] + (float)(ww + 1) + (float)(n % 3 - 1);
  float msk = q[18 + n];
  float fx = floorf(px), fy = floorf(py);
  float qlx = fminf(fmaxf(fx, 0.f), 29.f);
  float qly = fminf(fmaxf(fy, 0.f), 29.f);
  float qrx = fminf(fmaxf(fx + 1.f, 0.f), 29.f);
  float qry = fminf(fmaxf(fy + 1.f, 0.f), 29.f);
  float pxc = fminf(fmaxf(px, 0.f), 29.f);
  float pyc = fminf(fmaxf(py, 0.f), 29.f);
  float glt = (1.f + (qlx - pxc)) * (1.f + (qly - pyc));
  float grb = (1.f - (qrx - pxc)) * (1.f - (qry - pyc));
  float glb = (1.f + (qlx - pxc)) * (1.f - (qry - pyc));
  float grt = (1.f - (qrx - pxc)) * (1.f + (qly - pyc));
  int ax = (int)qlx, ay = (int)qly, bx = (int)qrx, by = (int)qry;
  int olt = 0, orb = 0, olb = 0, ort = 0;
  if (ax >= 1 && ax <= 28 && ay >= 1 && ay <= 28) olt = (ax-1)*WDIM + (ay-1); else glt = 0.f;
  if (bx >= 1 && bx <= 28 && by >= 1 && by <= 28) orb = (bx-1)*WDIM + (by-1); else grb = 0.f;
  if (ax >= 1 && ax <= 28 && by >= 1 && by <= 28) olb = (ax-1)*WDIM + (by-1); else glb = 0.f;
  if (bx >= 1 && bx <= 28 && ay >= 1 && ay <= 28) ort = (bx-1)*WDIM + (ay-1); else grt = 0.f;
  tabOff[i] = make_int4(olt, orb, olb, ort);
  tabG[i]   = make_float4(glt * msk, grb * msk, glb * msk, grt * msk);
}

// ---------------- sampler: build A^T[k=c*9+n][m] -------------------------
__global__ __launch_bounds__(256) void sample_kernel(
    const float* __restrict__ xin,   // [B][C][784]
    const int4* __restrict__ tabOff,
    const float4* __restrict__ tabG,
    float* __restrict__ A,           // [C*9][stride]
    int C, int mbase, int mcount, int stride)
{
  int mloc = blockIdx.x * 64 + (threadIdx.x & 63);
  if (mloc >= mcount) return;
  int c = blockIdx.y * 4 + (threadIdx.x >> 6);
  int m = mbase + mloc;
  int b = m / PIX;
  const float* xc = xin + ((size_t)b * C + c) * PIX;
  const int4*  to = tabOff + (size_t)m * NK;
  const float4* tg = tabG  + (size_t)m * NK;
  float* Ac = A + (size_t)c * NK * stride + mloc;
  #pragma unroll
  for (int n = 0; n < NK; ++n) {
    int4 o = to[n];
    float4 g = tg[n];
    float v = g.x * xc[o.x] + g.y * xc[o.y] + g.z * xc[o.z] + g.w * xc[o.w];
    Ac[(size_t)n * stride] = v;
  }
}

// ---------------- fp32 GEMM: out[m][o] = sum_k A^T[k][m] * Wt[o][k] -------
__global__ __launch_bounds__(256) void gemm_kernel(
    const float* __restrict__ A,   // [K][stride]
    const float* __restrict__ Wt,  // [O][K]
    float* __restrict__ out,       // [B][O][784]  (NCHW)
    int K, int O, int mbase, int mcount, int stride, int relu)
{
  __shared__ float As[16][64];
  __shared__ float Ws[16][68];     // stride 68 -> 2-way (free) bank pattern
  int m0 = blockIdx.x * 64, o0 = blockIdx.y * 64;
  int t = threadIdx.x;
  int tx = t & 15, ty = t >> 4;
  float acc[4][4] = {{0.f}};
  for (int k0 = 0; k0 < K; k0 += 16) {
    __syncthreads();
    {
      int kk = t >> 4, mg = (t & 15) * 4;
      const float* src = A + (size_t)(k0 + kk) * stride + m0 + mg;
      float4 v;
      if (m0 + mg + 3 < mcount) v = *(const float4*)src;
      else {
        v.x = (m0 + mg + 0 < mcount) ? src[0] : 0.f;
        v.y = (m0 + mg + 1 < mcount) ? src[1] : 0.f;
        v.z = (m0 + mg + 2 < mcount) ? src[2] : 0.f;
        v.w = (m0 + mg + 3 < mcount) ? src[3] : 0.f;
      }
      *(float4*)&As[kk][mg] = v;
    }
    {
      int oo = t >> 2, kg = (t & 3) * 4;
      float4 v = *(const float4*)&Wt[(size_t)(o0 + oo) * K + k0 + kg];
      Ws[kg + 0][oo] = v.x; Ws[kg + 1][oo] = v.y;
      Ws[kg + 2][oo] = v.z; Ws[kg + 3][oo] = v.w;
    }
    __syncthreads();
    #pragma unroll
    for (int kk = 0; kk < 16; ++kk) {
      float4 a4 = *(const float4*)&As[kk][tx * 4];
      float4 w4 = *(const float4*)&Ws[kk][ty * 4];
      float av[4] = {a4.x, a4.y, a4.z, a4.w};
      float wv[4] = {w4.x, w4.y, w4.z, w4.w};
      #pragma unroll
      for (int j = 0; j < 4; ++j)
        #pragma unroll
        for (int i = 0; i < 4; ++i)
          acc[j][i] += av[i] * wv[j];
    }
  }
  #pragma unroll
  for (int j = 0; j < 4; ++j) {
    int o = o0 + ty * 4 + j;
    #pragma unroll
    for (int i = 0; i < 4; ++i) {
      int mloc = m0 + tx * 4 + i;
      if (mloc >= mcount) continue;
      int m = mbase + mloc;
      int b = m / PIX, pix = m % PIX;
      float v = acc[j][i];
      if (relu) v = fmaxf(v, 0.f);
      out[((size_t)b * O + o) * PIX + pix] = v;
    }
  }
}

extern "C" void kernel_launch(void* const* d_in, const int* in_sizes, int n_in,
                              void* d_out, int out_size, void* d_ws, size_t ws_size,
                              hipStream_t stream)
{
  const float* x    = (const float*)d_in[0];
  const float* w_p1 = (const float*)d_in[1];
  const float* b_p1 = (const float*)d_in[2];
  const float* w_m1 = (const float*)d_in[3];
  const float* b_m1 = (const float*)d_in[4];
  const float* w_c1 = (const float*)d_in[5];
  const float* w_p2 = (const float*)d_in[6];
  const float* b_p2 = (const float*)d_in[7];
  const float* w_m2 = (const float*)d_in[8];
  const float* b_m2 = (const float*)d_in[9];
  const float* w_c2 = (const float*)d_in[10];
  float* out = (float*)d_out;

  char* ws = (char*)d_ws;
  auto align_up = [](size_t v) { return (v + 255) & ~(size_t)255; };
  size_t off = 0;
  float*  h    = (float*)(ws + off);  off += align_up((size_t)B * HID * PIX * 4);
  float*  pm1  = (float*)(ws + off);  off += align_up((size_t)M_TOT * 27 * 4);
  float*  pm2  = (float*)(ws + off);  off += align_up((size_t)M_TOT * 27 * 4);
  int4*   tabO = (int4*)(ws + off);   off += align_up((size_t)M_TOT * NK * 16);
  float4* tabG = (float4*)(ws + off); off += align_up((size_t)M_TOT * NK * 16);
  size_t avail = (ws_size > off) ? ws_size - off : 0;
  // chunk count per layer so the A^T buffer fits in remaining workspace
  int nc1 = 1;
  while (nc1 < 16 && (size_t)K1 * 4 * (M_TOT / nc1) > avail) nc1 <<= 1;
  int nc2 = 1;
  while (nc2 < 16 && (size_t)K2 * 4 * (M_TOT / nc2) > avail) nc2 <<= 1;
  float* Abuf = (float*)(ws + off);

  // ---- layer 1: x (C=256) -> h (1024), ReLU ----
  pconv_kernel<<<dim3(B * HH), dim3(768), 0, stream>>>(x, w_p1, b_p1, w_m1, b_m1, pm1, C1);
  mktab_kernel<<<dim3((M_TOT * NK + 255) / 256), dim3(256), 0, stream>>>(pm1, tabO, tabG);
  {
    int mc = M_TOT / nc1;
    for (int ci = 0; ci < nc1; ++ci) {
      int mbase = ci * mc;
      sample_kernel<<<dim3((mc + 63) / 64, C1 / 4), dim3(256), 0, stream>>>(
          x, tabO, tabG, Abuf, C1, mbase, mc, mc);
      gemm_kernel<<<dim3((mc + 63) / 64, HID / 64), dim3(256), 0, stream>>>(
          Abuf, w_c1, h, K1, HID, mbase, mc, mc, 1);
    }
  }
  // ---- layer 2: h (C=1024) -> out (256) ----
  pconv_kernel<<<dim3(B * HH), dim3(768), 0, stream>>>(h, w_p2, b_p2, w_m2, b_m2, pm2, HID);
  mktab_kernel<<<dim3((M_TOT * NK + 255) / 256), dim3(256), 0, stream>>>(pm2, tabO, tabG);
  {
    int mc = M_TOT / nc2;
    for (int ci = 0; ci < nc2; ++ci) {
      int mbase = ci * mc;
      sample_kernel<<<dim3((mc + 63) / 64, HID / 4), dim3(256), 0, stream>>>(
          h, tabO, tabG, Abuf, HID, mbase, mc, mc);
      gemm_kernel<<<dim3((mc + 63) / 64, 256 / 64), dim3(256), 0, stream>>>(
          Abuf, w_c2, out, K2, 256, mbase, mc, mc, 0);
    }
  }
}

// Round 2
// 632.904 us; speedup vs baseline: 2.8588x; 2.8588x over previous
//
#include <hip/hip_runtime.h>
#include <hip/hip_bf16.h>
#include <math.h>

#define B 8
#define HH 28
#define WDIM 28
#define PIX 784
#define M_TOT 6272
#define NK 9
#define C1 256
#define HID 1024
#define OUT2 256
#define K1 (C1*NK)   // 2304
#define K2 (HID*NK)  // 9216

typedef short short8_t __attribute__((ext_vector_type(8)));
typedef float f32x4 __attribute__((ext_vector_type(4)));
typedef unsigned short us4v __attribute__((ext_vector_type(4)));

__device__ inline float bf2f(unsigned short u){ union{unsigned i; float f;} w; w.i=((unsigned)u)<<16; return w.f; }
__device__ inline unsigned short f2bf(float f){ union{float ff; unsigned i;} w; w.ff=f; unsigned u=w.i; return (unsigned short)((u + 0x7FFFu + ((u>>16)&1u))>>16); }

__device__ inline void gload16(const void* g, void* l) {
  __builtin_amdgcn_global_load_lds((const __attribute__((address_space(1))) void*)g,
                                   (__attribute__((address_space(3))) void*)l, 16, 0, 0);
}

// ---------------- NCHW fp32 pconv (layer 1) ----------------
__global__ __launch_bounds__(768) void pconv_kernel(
    const float* __restrict__ x, const float* __restrict__ w_p,
    const float* __restrict__ b_p, const float* __restrict__ w_m,
    const float* __restrict__ b_m, float* __restrict__ pm, int C)
{
  __shared__ float xs[16][3][32];
  int bh = blockIdx.x;
  int b = bh / HH, h = bh % HH;
  int t = threadIdx.x;
  int ch = t / WDIM, w = t % WDIM;
  bool active = (t < 27 * WDIM);
  float acc = 0.f;
  const float* wbase = nullptr;
  if (active) {
    if (ch < 18) { acc = b_p[ch];      wbase = w_p + (size_t)ch * C * 9; }
    else         { acc = b_m[ch - 18]; wbase = w_m + (size_t)(ch - 18) * C * 9; }
  }
  for (int cc = 0; cc < C; cc += 16) {
    __syncthreads();
    for (int i = t; i < 16 * 3 * 30; i += 768) {
      int c = i / 90, rem = i % 90, r = rem / 30, wc = rem % 30;
      int hy = h + r - 1, wx = wc - 1;
      float v = 0.f;
      if (hy >= 0 && hy < HH && wx >= 0 && wx < WDIM)
        v = x[(((size_t)b * C + (cc + c)) * HH + hy) * WDIM + wx];
      xs[c][r][wc] = v;
    }
    __syncthreads();
    if (active) {
      const float* wp = wbase + (size_t)cc * 9;
      #pragma unroll 4
      for (int c = 0; c < 16; ++c) {
        const float* wr = wp + (size_t)c * 9;
        float s = 0.f;
        #pragma unroll
        for (int r = 0; r < 3; ++r)
          #pragma unroll
          for (int q = 0; q < 3; ++q)
            s += xs[c][r][w + q] * wr[r * 3 + q];
        acc += s;
      }
    }
  }
  if (active) {
    if (ch >= 18) acc = 1.f / (1.f + expf(-acc));
    pm[(size_t)(b * PIX + h * WDIM + w) * 27 + ch] = acc;
  }
}

// ---------------- channels-last bf16 pconv (layer 2) ----------------
__global__ __launch_bounds__(768) void pconv_cl_kernel(
    const unsigned short* __restrict__ xcl, // [B][784][C] bf16
    const float* __restrict__ wt,           // [27][9][C]
    const float* __restrict__ b_p, const float* __restrict__ b_m,
    float* __restrict__ pm, int C)
{
  __shared__ unsigned short xs[3][30][24];  // stride 24 (48B) to spread banks
  int bh = blockIdx.x;
  int b = bh / HH, h = bh % HH;
  int t = threadIdx.x;
  int ch = t / WDIM, w = t % WDIM;
  bool active = (t < 27 * WDIM);
  float acc = 0.f;
  if (active) acc = (ch < 18) ? b_p[ch] : b_m[ch - 18];
  const float* wch = wt + (size_t)ch * 9 * C;
  for (int cc = 0; cc < C; cc += 16) {
    __syncthreads();
    for (int e = t; e < 1440; e += 768) {
      int c_i = e & 15, wc = (e >> 4) % 30, r = e / 480;
      int hy = h + r - 1, wx = wc - 1;
      unsigned short v = 0;
      if (hy >= 0 && hy < HH && wx >= 0 && wx < WDIM)
        v = xcl[((size_t)b * PIX + hy * WDIM + wx) * C + cc + c_i];
      xs[r][wc][c_i] = v;
    }
    __syncthreads();
    if (active) {
      #pragma unroll
      for (int r = 0; r < 3; ++r)
        #pragma unroll
        for (int q = 0; q < 3; ++q) {
          const float* wrow = wch + (r * 3 + q) * C + cc;
          short8_t x0 = *(const short8_t*)&xs[r][w + q][0];
          short8_t x1 = *(const short8_t*)&xs[r][w + q][8];
          #pragma unroll
          for (int c = 0; c < 8; ++c) acc += bf2f((unsigned short)x0[c]) * wrow[c];
          #pragma unroll
          for (int c = 0; c < 8; ++c) acc += bf2f((unsigned short)x1[c]) * wrow[c + 8];
        }
    }
  }
  if (active) {
    if (ch >= 18) acc = 1.f / (1.f + expf(-acc));
    pm[(size_t)(b * PIX + h * WDIM + w) * 27 + ch] = acc;
  }
}

// ---------------- bilinear table ----------------
__global__ __launch_bounds__(256) void mktab_kernel(
    const float* __restrict__ pm,
    int4* __restrict__ tabOff, float4* __restrict__ tabG)
{
  int i = blockIdx.x * 256 + threadIdx.x;
  if (i >= M_TOT * NK) return;
  int m = i / NK, n = i % NK;
  int pix = m % PIX;
  int hh = pix / WDIM, ww = pix % WDIM;
  const float* q = pm + (size_t)m * 27;
  float px = q[n]     + (float)(hh + 1) + (float)(n / 3 - 1);
  float py = q[9 + n] + (float)(ww + 1) + (float)(n % 3 - 1);
  float msk = q[18 + n];
  float fx = floorf(px), fy = floorf(py);
  float qlx = fminf(fmaxf(fx, 0.f), 29.f);
  float qly = fminf(fmaxf(fy, 0.f), 29.f);
  float qrx = fminf(fmaxf(fx + 1.f, 0.f), 29.f);
  float qry = fminf(fmaxf(fy + 1.f, 0.f), 29.f);
  float pxc = fminf(fmaxf(px, 0.f), 29.f);
  float pyc = fminf(fmaxf(py, 0.f), 29.f);
  float glt = (1.f + (qlx - pxc)) * (1.f + (qly - pyc));
  float grb = (1.f - (qrx - pxc)) * (1.f - (qry - pyc));
  float glb = (1.f + (qlx - pxc)) * (1.f - (qry - pyc));
  float grt = (1.f - (qrx - pxc)) * (1.f + (qly - pyc));
  int ax = (int)qlx, ay = (int)qly, bx = (int)qrx, by = (int)qry;
  int olt = 0, orb = 0, olb = 0, ort = 0;
  if (ax >= 1 && ax <= 28 && ay >= 1 && ay <= 28) olt = (ax-1)*WDIM + (ay-1); else glt = 0.f;
  if (bx >= 1 && bx <= 28 && by >= 1 && by <= 28) orb = (bx-1)*WDIM + (by-1); else grb = 0.f;
  if (ax >= 1 && ax <= 28 && by >= 1 && by <= 28) olb = (ax-1)*WDIM + (by-1); else glb = 0.f;
  if (bx >= 1 && bx <= 28 && ay >= 1 && ay <= 28) ort = (bx-1)*WDIM + (ay-1); else grt = 0.f;
  tabOff[i] = make_int4(olt, orb, olb, ort);
  tabG[i]   = make_float4(glt * msk, grb * msk, glb * msk, grt * msk);
}

// ---------------- transpose x: [B][C][784] fp32 -> [B][784][C] bf16 -------
__global__ __launch_bounds__(256) void xpose_kernel(
    const float* __restrict__ x, unsigned short* __restrict__ xcl, int C)
{
  __shared__ unsigned short tile[32][33];
  int b = blockIdx.z, c0 = blockIdx.y * 32, p0 = blockIdx.x * 32;
  int tx = threadIdx.x & 31, ty = threadIdx.x >> 5;
  for (int i = ty; i < 32; i += 8) {
    int c = c0 + i, p = p0 + tx;
    unsigned short v = 0;
    if (p < PIX) v = f2bf(x[((size_t)b * C + c) * PIX + p]);
    tile[i][tx] = v;
  }
  __syncthreads();
  for (int i = ty; i < 32; i += 8) {
    int p = p0 + i, c = c0 + tx;
    if (p < PIX) xcl[((size_t)b * PIX + p) * C + c] = tile[tx][i];
  }
}

// ---------------- weight repack: [O][C][9] fp32 -> [O][n*C+c] bf16 --------
__global__ __launch_bounds__(256) void wrep_kernel(
    const float* __restrict__ w, unsigned short* __restrict__ wr, int C)
{
  int o = blockIdx.x;
  int K = 9 * C;
  for (int k = threadIdx.x; k < K; k += 256) {
    int n = k / C, c = k % C;
    wr[(size_t)o * K + k] = f2bf(w[((size_t)o * C + c) * 9 + n]);
  }
}

// ---------------- pconv weight repack: -> [27][9][C] fp32 -----------------
__global__ __launch_bounds__(256) void prep_pw_kernel(
    const float* __restrict__ wp, const float* __restrict__ wm,
    float* __restrict__ wt, int C)
{
  int ch = blockIdx.x;
  const float* src = (ch < 18) ? wp + (size_t)ch * C * 9 : wm + (size_t)(ch - 18) * C * 9;
  for (int i = threadIdx.x; i < 9 * C; i += 256) {
    int rq = i / C, c = i % C;
    wt[(size_t)ch * 9 * C + i] = src[(size_t)c * 9 + rq];
  }
}

// ---------------- sampler: channels-last gathers -> A[m][k=n*C+c] bf16 ----
__global__ __launch_bounds__(256) void sample_cl_kernel(
    const unsigned short* __restrict__ xcl, // [B][784][C] bf16
    const int4* __restrict__ tabO, const float4* __restrict__ tabG,
    unsigned short* __restrict__ A,          // [mc][9*C]
    int C, int mbase)
{
  int mi = threadIdx.x >> 6, lane = threadIdx.x & 63;
  int mloc = blockIdx.x * 4 + mi;
  int m = mbase + mloc;
  int b = m / PIX;
  const int4*  to = tabO + (size_t)m * NK;
  const float4* tg = tabG + (size_t)m * NK;
  int K = NK * C;
  unsigned short* Arow = A + (size_t)mloc * K;
  #pragma unroll
  for (int n = 0; n < NK; ++n) {
    int4 o = to[n]; float4 g = tg[n];
    const unsigned short* p0 = xcl + ((size_t)b * PIX + o.x) * C;
    const unsigned short* p1 = xcl + ((size_t)b * PIX + o.y) * C;
    const unsigned short* p2 = xcl + ((size_t)b * PIX + o.z) * C;
    const unsigned short* p3 = xcl + ((size_t)b * PIX + o.w) * C;
    for (int c0 = lane * 4; c0 < C; c0 += 256) {
      us4v a0 = *(const us4v*)(p0 + c0);
      us4v a1 = *(const us4v*)(p1 + c0);
      us4v a2 = *(const us4v*)(p2 + c0);
      us4v a3 = *(const us4v*)(p3 + c0);
      us4v r;
      #pragma unroll
      for (int j = 0; j < 4; ++j) {
        float v = g.x * bf2f(a0[j]) + g.y * bf2f(a1[j])
                + g.z * bf2f(a2[j]) + g.w * bf2f(a3[j]);
        r[j] = f2bf(v);
      }
      *(us4v*)(Arow + n * C + c0) = r;
    }
  }
}

// ---------------- MFMA GEMM -----------------------------------------------
// A: [mc][K] bf16 row-major, Wr: [O][K] bf16 row-major.
// VAR=0: D row=m, col=o -> write h_cl [m][O] bf16 + ReLU (lanes || o)
// VAR=1: D row=o, col=m -> write NCHW fp32 out (lanes || pix)
template<int TN, int VAR>
__global__ __launch_bounds__(256) void gemm_mfma(
    const unsigned short* __restrict__ A,
    const unsigned short* __restrict__ Wr,
    void* __restrict__ outv,
    int K, int O, int mbase)
{
  __shared__ unsigned short As[128 * 64];
  __shared__ unsigned short Ws[TN * 64];
  constexpr int NFO = TN / 32;
  int t = threadIdx.x, lane = t & 63, wv = t >> 6;
  int m0 = blockIdx.x * 128, o0 = blockIdx.y * TN;
  int wm = (wv & 1) * 64, wo = (wv >> 1) * (TN / 2);
  f32x4 acc[4][NFO];
  #pragma unroll
  for (int i = 0; i < 4; ++i)
    #pragma unroll
    for (int j = 0; j < NFO; ++j)
      acc[i][j] = {0.f, 0.f, 0.f, 0.f};

  for (int k0 = 0; k0 < K; k0 += 64) {
    __syncthreads();
    #pragma unroll
    for (int i = 0; i < 4; ++i) {        // A tile: 128 rows x 128B
      int L = i * 256 + t;
      int row = L >> 3, ch = L & 7;
      const char* src = (const char*)(A + (size_t)(m0 + row) * K + k0) + ((ch ^ (row & 7)) << 4);
      gload16(src, (char*)As + (size_t)(i * 256 + (wv << 6)) * 16);
    }
    #pragma unroll
    for (int i = 0; i < TN / 32; ++i) {  // W tile: TN rows x 128B
      int L = i * 256 + t;
      int row = L >> 3, ch = L & 7;
      const char* src = (const char*)(Wr + (size_t)(o0 + row) * K + k0) + ((ch ^ (row & 7)) << 4);
      gload16(src, (char*)Ws + (size_t)(i * 256 + (wv << 6)) * 16);
    }
    __syncthreads();
    #pragma unroll
    for (int ks = 0; ks < 2; ++ks) {
      short8_t af[4], bfq[NFO];
      #pragma unroll
      for (int fm = 0; fm < 4; ++fm) {
        int row = wm + fm * 16 + (lane & 15);
        int ch = ks * 4 + (lane >> 4);
        af[fm] = *(const short8_t*)((const char*)As + row * 128 + ((ch ^ (row & 7)) << 4));
      }
      #pragma unroll
      for (int fo = 0; fo < NFO; ++fo) {
        int row = wo + fo * 16 + (lane & 15);
        int ch = ks * 4 + (lane >> 4);
        bfq[fo] = *(const short8_t*)((const char*)Ws + row * 128 + ((ch ^ (row & 7)) << 4));
      }
      #pragma unroll
      for (int fm = 0; fm < 4; ++fm)
        #pragma unroll
        for (int fo = 0; fo < NFO; ++fo)
          acc[fm][fo] = (VAR == 0)
            ? __builtin_amdgcn_mfma_f32_16x16x32_bf16(af[fm], bfq[fo], acc[fm][fo], 0, 0, 0)
            : __builtin_amdgcn_mfma_f32_16x16x32_bf16(bfq[fo], af[fm], acc[fm][fo], 0, 0, 0);
    }
  }

  if (VAR == 0) {
    unsigned short* hcl = (unsigned short*)outv;
    #pragma unroll
    for (int fm = 0; fm < 4; ++fm)
      #pragma unroll
      for (int fo = 0; fo < NFO; ++fo)
        #pragma unroll
        for (int r = 0; r < 4; ++r) {
          int ml = m0 + wm + fm * 16 + (lane >> 4) * 4 + r;
          int o  = o0 + wo + fo * 16 + (lane & 15);
          float v = fmaxf(acc[fm][fo][r], 0.f);
          hcl[(size_t)(mbase + ml) * O + o] = f2bf(v);
        }
  } else {
    float* outp = (float*)outv;
    #pragma unroll
    for (int fm = 0; fm < 4; ++fm)
      #pragma unroll
      for (int fo = 0; fo < NFO; ++fo)
        #pragma unroll
        for (int r = 0; r < 4; ++r) {
          int o  = o0 + wo + fo * 16 + (lane >> 4) * 4 + r;
          int ml = m0 + wm + fm * 16 + (lane & 15);
          int m = mbase + ml;
          int b = m / PIX, pix = m % PIX;
          outp[((size_t)b * O + o) * PIX + pix] = acc[fm][fo][r];
        }
  }
}

extern "C" void kernel_launch(void* const* d_in, const int* in_sizes, int n_in,
                              void* d_out, int out_size, void* d_ws, size_t ws_size,
                              hipStream_t stream)
{
  const float* x    = (const float*)d_in[0];
  const float* w_p1 = (const float*)d_in[1];
  const float* b_p1 = (const float*)d_in[2];
  const float* w_m1 = (const float*)d_in[3];
  const float* b_m1 = (const float*)d_in[4];
  const float* w_c1 = (const float*)d_in[5];
  const float* w_p2 = (const float*)d_in[6];
  const float* b_p2 = (const float*)d_in[7];
  const float* w_m2 = (const float*)d_in[8];
  const float* b_m2 = (const float*)d_in[9];
  const float* w_c2 = (const float*)d_in[10];
  float* out = (float*)d_out;

  char* ws = (char*)d_ws;
  auto align_up = [](size_t v) { return (v + 255) & ~(size_t)255; };
  size_t off = 0;
  unsigned short* hcl = (unsigned short*)(ws + off); off += align_up((size_t)M_TOT * HID * 2);
  float* pm1 = (float*)(ws + off); off += align_up((size_t)M_TOT * 27 * 4);
  float* pm2 = (float*)(ws + off); off += align_up((size_t)M_TOT * 27 * 4);
  int4*   tabO = (int4*)(ws + off);   off += align_up((size_t)M_TOT * NK * 16);
  float4* tabG = (float4*)(ws + off); off += align_up((size_t)M_TOT * NK * 16);
  unsigned short* xcl = (unsigned short*)(ws + off); off += align_up((size_t)M_TOT * C1 * 2);
  unsigned short* wr1 = (unsigned short*)(ws + off); off += align_up((size_t)HID * K1 * 2);
  unsigned short* wr2 = (unsigned short*)(ws + off); off += align_up((size_t)OUT2 * K2 * 2);
  float* wt2 = (float*)(ws + off); off += align_up((size_t)27 * 9 * HID * 4);
  unsigned short* Abuf = (unsigned short*)(ws + off);
  size_t avail = (ws_size > off) ? ws_size - off : 0;
  auto pick_nc = [&](size_t K) {
    const int cands[3] = {1, 7, 49};
    for (int i = 0; i < 3; ++i)
      if ((size_t)(M_TOT / cands[i]) * K * 2 <= avail) return cands[i];
    return 49;
  };
  int nc1 = pick_nc(K1), nc2 = pick_nc(K2);

  // prep
  xpose_kernel<<<dim3(25, C1/32, B), 256, 0, stream>>>(x, xcl, C1);
  wrep_kernel<<<HID, 256, 0, stream>>>(w_c1, wr1, C1);
  wrep_kernel<<<OUT2, 256, 0, stream>>>(w_c2, wr2, HID);
  prep_pw_kernel<<<27, 256, 0, stream>>>(w_p2, w_m2, wt2, HID);

  // ---- layer 1 ----
  pconv_kernel<<<B * HH, 768, 0, stream>>>(x, w_p1, b_p1, w_m1, b_m1, pm1, C1);
  mktab_kernel<<<(M_TOT * NK + 255) / 256, 256, 0, stream>>>(pm1, tabO, tabG);
  {
    int mc = M_TOT / nc1;
    for (int ci = 0; ci < nc1; ++ci) {
      int mb = ci * mc;
      sample_cl_kernel<<<mc / 4, 256, 0, stream>>>(xcl, tabO, tabG, Abuf, C1, mb);
      gemm_mfma<128, 0><<<dim3(mc / 128, HID / 128), 256, 0, stream>>>(
          Abuf, wr1, hcl, K1, HID, mb);
    }
  }
  // ---- layer 2 ----
  pconv_cl_kernel<<<B * HH, 768, 0, stream>>>(hcl, wt2, b_p2, b_m2, pm2, HID);
  mktab_kernel<<<(M_TOT * NK + 255) / 256, 256, 0, stream>>>(pm2, tabO, tabG);
  {
    int mc = M_TOT / nc2;
    for (int ci = 0; ci < nc2; ++ci) {
      int mb = ci * mc;
      sample_cl_kernel<<<mc / 4, 256, 0, stream>>>(hcl, tabO, tabG, Abuf, HID, mb);
      gemm_mfma<64, 1><<<dim3(mc / 128, OUT2 / 64), 256, 0, stream>>>(
          Abuf, wr2, out, K2, OUT2, mb);
    }
  }
}

// Round 3
// 293.857 us; speedup vs baseline: 6.1573x; 2.1538x over previous
//
#include <hip/hip_runtime.h>
#include <hip/hip_bf16.h>
#include <math.h>

#define B 8
#define HH 28
#define WDIM 28
#define PIX 784
#define PPIX 900          // 30*30 padded
#define M_TOT 6272
#define NK 9
#define C1 256
#define HID 1024
#define OUT2 256
#define K1 (C1*NK)   // 2304
#define K2 (HID*NK)  // 9216

typedef short short8_t __attribute__((ext_vector_type(8)));
typedef float f32x4 __attribute__((ext_vector_type(4)));
typedef unsigned short us4v __attribute__((ext_vector_type(4)));
typedef unsigned int u32x4 __attribute__((ext_vector_type(4)));

__device__ inline float bf2f(unsigned short u){ union{unsigned i; float f;} w; w.i=((unsigned)u)<<16; return w.f; }
__device__ inline unsigned short f2bf(float f){ union{float ff; unsigned i;} w; w.ff=f; unsigned u=w.i; return (unsigned short)((u + 0x7FFFu + ((u>>16)&1u))>>16); }

__device__ inline void gload16(const void* g, void* l) {
  __builtin_amdgcn_global_load_lds((const __attribute__((address_space(1))) void*)g,
                                   (__attribute__((address_space(3))) void*)l, 16, 0, 0);
}

// ---------------- zero fill (for pad rings) ----------------
__global__ __launch_bounds__(256) void zero_kernel(u32x4* __restrict__ p, int n16)
{
  int i = blockIdx.x * 256 + threadIdx.x;
  if (i < n16) p[i] = u32x4{0u, 0u, 0u, 0u};
}

// ---------------- transpose x: [B][C][784] fp32 -> padded [B][900][C] bf16
__global__ __launch_bounds__(256) void xpose_kernel(
    const float* __restrict__ x, unsigned short* __restrict__ xclp, int C)
{
  __shared__ unsigned short tile[32][33];
  int b = blockIdx.z, c0 = blockIdx.y * 32, p0 = blockIdx.x * 32;
  int tx = threadIdx.x & 31, ty = threadIdx.x >> 5;
  for (int i = ty; i < 32; i += 8) {
    int c = c0 + i, p = p0 + tx;
    unsigned short v = 0;
    if (p < PIX) v = f2bf(x[((size_t)b * C + c) * PIX + p]);
    tile[i][tx] = v;
  }
  __syncthreads();
  for (int i = ty; i < 32; i += 8) {
    int p = p0 + i, c = c0 + tx;
    if (p < PIX) {
      int h = p / WDIM, w = p % WDIM;
      xclp[((size_t)b * PPIX + (h + 1) * 30 + (w + 1)) * C + c] = tile[tx][i];
    }
  }
}

// ---------------- w_c repack: [O][C][9] fp32 -> [O][n*C+c] bf16 -----------
__global__ __launch_bounds__(256) void wrep_kernel(
    const float* __restrict__ w, unsigned short* __restrict__ wr, int C)
{
  int o = blockIdx.x;
  int K = 9 * C;
  for (int k = threadIdx.x; k < K; k += 256) {
    int n = k / C, c = k % C;
    wr[(size_t)o * K + k] = f2bf(w[((size_t)o * C + c) * 9 + n]);
  }
}

// ---------------- pconv weight repack: -> [32][9*C] bf16 (rows 27..31 = 0)
__global__ __launch_bounds__(256) void wprep_kernel(
    const float* __restrict__ wp, const float* __restrict__ wm,
    unsigned short* __restrict__ wpr, int C)
{
  int ch = blockIdx.x;
  int K = 9 * C;
  const float* src = nullptr;
  if (ch < 18) src = wp + (size_t)ch * C * 9;
  else if (ch < 27) src = wm + (size_t)(ch - 18) * C * 9;
  for (int k = threadIdx.x; k < K; k += 256) {
    int n = k / C, c = k % C;
    unsigned short v = 0;
    if (src) v = f2bf(src[(size_t)c * 9 + n]);
    wpr[(size_t)ch * K + k] = v;
  }
}

// ---------------- pconv as skinny MFMA GEMM: [M][9C] x [32][9C]^T --------
template<int C, int KSPLIT>
__global__ __launch_bounds__(256) void pconv_mfma(
    const unsigned short* __restrict__ xclp, // [B*900][C] padded
    const unsigned short* __restrict__ wpr,  // [32][9C]
    float* __restrict__ pmpart)              // [KSPLIT][M][32]
{
  __shared__ unsigned short As[128 * 64];
  __shared__ unsigned short Ws[32 * 64];
  const int K = 9 * C;
  int t = threadIdx.x, lane = t & 63, wv = t >> 6;
  int m0 = blockIdx.x * 128;
  int kz = blockIdx.y;
  int wm = (wv & 1) * 64, wo = (wv >> 1) * 16;
  f32x4 acc[4];
  #pragma unroll
  for (int i = 0; i < 4; ++i) acc[i] = {0.f, 0.f, 0.f, 0.f};
  long pbase[4];
  #pragma unroll
  for (int i = 0; i < 4; ++i) {
    int L = i * 256 + t, row = L >> 3;
    int m = m0 + row, b = m / PIX, pix = m - b * PIX;
    int h = pix / WDIM, w = pix - h * WDIM;
    pbase[i] = ((long)b * PPIX + (h + 1) * 30 + (w + 1)) * C;
  }
  int kbeg = kz * (K / KSPLIT), kend = kbeg + K / KSPLIT;
  for (int k0 = kbeg; k0 < kend; k0 += 64) {
    int n = k0 / C, c0 = k0 - n * C;
    long doff = (long)(((n / 3) - 1) * 30 + (n % 3) - 1) * C + c0;
    __syncthreads();
    #pragma unroll
    for (int i = 0; i < 4; ++i) {
      int L = i * 256 + t, row = L >> 3, ch = L & 7;
      const char* src = (const char*)(xclp + pbase[i] + doff) + ((ch ^ (row & 7)) << 4);
      gload16(src, (char*)As + (size_t)(i * 256 + (wv << 6)) * 16);
    }
    {
      int row = t >> 3, ch = t & 7;
      const char* src = (const char*)(wpr + (size_t)row * K + k0) + ((ch ^ (row & 7)) << 4);
      gload16(src, (char*)Ws + (size_t)(wv << 6) * 16);
    }
    __syncthreads();
    #pragma unroll
    for (int ks = 0; ks < 2; ++ks) {
      short8_t af[4], bq;
      {
        int row = wo + (lane & 15), ch = ks * 4 + (lane >> 4);
        bq = *(const short8_t*)((const char*)Ws + row * 128 + ((ch ^ (row & 7)) << 4));
      }
      #pragma unroll
      for (int fm = 0; fm < 4; ++fm) {
        int row = wm + fm * 16 + (lane & 15), ch = ks * 4 + (lane >> 4);
        af[fm] = *(const short8_t*)((const char*)As + row * 128 + ((ch ^ (row & 7)) << 4));
      }
      #pragma unroll
      for (int fm = 0; fm < 4; ++fm)
        acc[fm] = __builtin_amdgcn_mfma_f32_16x16x32_bf16(af[fm], bq, acc[fm], 0, 0, 0);
    }
  }
  float* dst = pmpart + (size_t)kz * M_TOT * 32;
  #pragma unroll
  for (int fm = 0; fm < 4; ++fm)
    #pragma unroll
    for (int r = 0; r < 4; ++r) {
      int ml = m0 + wm + fm * 16 + (lane >> 4) * 4 + r;
      int o = wo + (lane & 15);
      dst[(size_t)ml * 32 + o] = acc[fm][r];
    }
}

// ---------------- bilinear table (padded 30x30 coords, bias+sigmoid here) -
template<int KSPLIT>
__global__ __launch_bounds__(256) void mktab_kernel(
    const float* __restrict__ pmpart,
    const float* __restrict__ b_p, const float* __restrict__ b_m,
    int4* __restrict__ tabOff, float4* __restrict__ tabG)
{
  int i = blockIdx.x * 256 + threadIdx.x;
  if (i >= M_TOT * NK) return;
  int m = i / NK, n = i % NK;
  int pix = m % PIX;
  int hh = pix / WDIM, ww = pix % WDIM;
  float ox = 0.f, oy = 0.f, om = 0.f;
  #pragma unroll
  for (int kz = 0; kz < KSPLIT; ++kz) {
    const float* q = pmpart + (size_t)kz * M_TOT * 32 + (size_t)m * 32;
    ox += q[n]; oy += q[9 + n]; om += q[18 + n];
  }
  float px = ox + b_p[n]     + (float)(hh + 1) + (float)(n / 3 - 1);
  float py = oy + b_p[9 + n] + (float)(ww + 1) + (float)(n % 3 - 1);
  float msk = 1.f / (1.f + expf(-(om + b_m[n])));
  float fx = floorf(px), fy = floorf(py);
  float qlx = fminf(fmaxf(fx, 0.f), 29.f);
  float qly = fminf(fmaxf(fy, 0.f), 29.f);
  float qrx = fminf(fmaxf(fx + 1.f, 0.f), 29.f);
  float qry = fminf(fmaxf(fy + 1.f, 0.f), 29.f);
  float pxc = fminf(fmaxf(px, 0.f), 29.f);
  float pyc = fminf(fmaxf(py, 0.f), 29.f);
  float glt = (1.f + (qlx - pxc)) * (1.f + (qly - pyc));
  float grb = (1.f - (qrx - pxc)) * (1.f - (qry - pyc));
  float glb = (1.f + (qlx - pxc)) * (1.f - (qry - pyc));
  float grt = (1.f - (qrx - pxc)) * (1.f + (qly - pyc));
  int ax = (int)qlx, ay = (int)qly, bx = (int)qrx, by = (int)qry;
  tabOff[i] = make_int4(ax * 30 + ay, bx * 30 + by, ax * 30 + by, bx * 30 + ay);
  tabG[i]   = make_float4(glt * msk, grb * msk, glb * msk, grt * msk);
}

// ---------------- sampler: padded gathers -> A[m][k=n*C+c] bf16 ----------
__global__ __launch_bounds__(256) void sample_cl_kernel(
    const unsigned short* __restrict__ xclp, // [B*900][C] padded
    const int4* __restrict__ tabO, const float4* __restrict__ tabG,
    unsigned short* __restrict__ A,          // [mc][9*C]
    int C, int mbase)
{
  int mi = threadIdx.x >> 6, lane = threadIdx.x & 63;
  int mloc = blockIdx.x * 4 + mi;
  int m = mbase + mloc;
  int b = m / PIX;
  const int4*  to = tabO + (size_t)m * NK;
  const float4* tg = tabG + (size_t)m * NK;
  int K = NK * C;
  unsigned short* Arow = A + (size_t)mloc * K;
  const unsigned short* xb = xclp + (size_t)b * PPIX * C;
  #pragma unroll
  for (int n = 0; n < NK; ++n) {
    int4 o = to[n]; float4 g = tg[n];
    const unsigned short* p0 = xb + (size_t)o.x * C;
    const unsigned short* p1 = xb + (size_t)o.y * C;
    const unsigned short* p2 = xb + (size_t)o.z * C;
    const unsigned short* p3 = xb + (size_t)o.w * C;
    for (int c0 = lane * 4; c0 < C; c0 += 256) {
      us4v a0 = *(const us4v*)(p0 + c0);
      us4v a1 = *(const us4v*)(p1 + c0);
      us4v a2 = *(const us4v*)(p2 + c0);
      us4v a3 = *(const us4v*)(p3 + c0);
      us4v r;
      #pragma unroll
      for (int j = 0; j < 4; ++j) {
        float v = g.x * bf2f(a0[j]) + g.y * bf2f(a1[j])
                + g.z * bf2f(a2[j]) + g.w * bf2f(a3[j]);
        r[j] = f2bf(v);
      }
      *(us4v*)(Arow + n * C + c0) = r;
    }
  }
}

// ---------------- MFMA GEMM ----------------------------------------------
// A: [mc][K] bf16, Wr: [O][K] bf16.
// VAR=0: out = padded hclp [B*900][O] bf16 (+ReLU), ksplit must be 1
// VAR=1: out = fp32 partials [ksplit][B][O][784] NCHW
template<int TN, int VAR>
__global__ __launch_bounds__(256) void gemm_mfma(
    const unsigned short* __restrict__ A,
    const unsigned short* __restrict__ Wr,
    void* __restrict__ outv,
    int K, int O, int mbase, int ksplit)
{
  __shared__ unsigned short As[128 * 64];
  __shared__ unsigned short Ws[TN * 64];
  constexpr int NFO = TN / 32;
  int t = threadIdx.x, lane = t & 63, wv = t >> 6;
  int m0 = blockIdx.x * 128, o0 = blockIdx.y * TN;
  int kz = blockIdx.z;
  int wm = (wv & 1) * 64, wo = (wv >> 1) * (TN / 2);
  f32x4 acc[4][NFO];
  #pragma unroll
  for (int i = 0; i < 4; ++i)
    #pragma unroll
    for (int j = 0; j < NFO; ++j)
      acc[i][j] = {0.f, 0.f, 0.f, 0.f};

  int kn = K / ksplit;
  int kbeg = kz * kn, kend = kbeg + kn;
  for (int k0 = kbeg; k0 < kend; k0 += 64) {
    __syncthreads();
    #pragma unroll
    for (int i = 0; i < 4; ++i) {
      int L = i * 256 + t, row = L >> 3, ch = L & 7;
      const char* src = (const char*)(A + (size_t)(m0 + row) * K + k0) + ((ch ^ (row & 7)) << 4);
      gload16(src, (char*)As + (size_t)(i * 256 + (wv << 6)) * 16);
    }
    #pragma unroll
    for (int i = 0; i < TN / 32; ++i) {
      int L = i * 256 + t, row = L >> 3, ch = L & 7;
      const char* src = (const char*)(Wr + (size_t)(o0 + row) * K + k0) + ((ch ^ (row & 7)) << 4);
      gload16(src, (char*)Ws + (size_t)(i * 256 + (wv << 6)) * 16);
    }
    __syncthreads();
    #pragma unroll
    for (int ks = 0; ks < 2; ++ks) {
      short8_t af[4], bfq[NFO];
      #pragma unroll
      for (int fm = 0; fm < 4; ++fm) {
        int row = wm + fm * 16 + (lane & 15), ch = ks * 4 + (lane >> 4);
        af[fm] = *(const short8_t*)((const char*)As + row * 128 + ((ch ^ (row & 7)) << 4));
      }
      #pragma unroll
      for (int fo = 0; fo < NFO; ++fo) {
        int row = wo + fo * 16 + (lane & 15), ch = ks * 4 + (lane >> 4);
        bfq[fo] = *(const short8_t*)((const char*)Ws + row * 128 + ((ch ^ (row & 7)) << 4));
      }
      #pragma unroll
      for (int fm = 0; fm < 4; ++fm)
        #pragma unroll
        for (int fo = 0; fo < NFO; ++fo)
          acc[fm][fo] = (VAR == 0)
            ? __builtin_amdgcn_mfma_f32_16x16x32_bf16(af[fm], bfq[fo], acc[fm][fo], 0, 0, 0)
            : __builtin_amdgcn_mfma_f32_16x16x32_bf16(bfq[fo], af[fm], acc[fm][fo], 0, 0, 0);
    }
  }

  if (VAR == 0) {
    unsigned short* hcl = (unsigned short*)outv;
    #pragma unroll
    for (int fm = 0; fm < 4; ++fm)
      #pragma unroll
      for (int r = 0; r < 4; ++r) {
        int ml = m0 + wm + fm * 16 + (lane >> 4) * 4 + r;
        int m = mbase + ml, b = m / PIX, pix = m - b * PIX;
        int h = pix / WDIM, w = pix - h * WDIM;
        size_t base = ((size_t)b * PPIX + (h + 1) * 30 + (w + 1)) * (size_t)O;
        #pragma unroll
        for (int fo = 0; fo < NFO; ++fo) {
          int o = o0 + wo + fo * 16 + (lane & 15);
          hcl[base + o] = f2bf(fmaxf(acc[fm][fo][r], 0.f));
        }
      }
  } else {
    float* outp = (float*)outv + (size_t)kz * M_TOT * O;
    #pragma unroll
    for (int fm = 0; fm < 4; ++fm) {
      int ml = m0 + wm + fm * 16 + (lane & 15);
      int m = mbase + ml, b = m / PIX, pix = m - b * PIX;
      #pragma unroll
      for (int fo = 0; fo < NFO; ++fo)
        #pragma unroll
        for (int r = 0; r < 4; ++r) {
          int o = o0 + wo + fo * 16 + (lane >> 4) * 4 + r;
          outp[((size_t)b * O + o) * PIX + pix] = acc[fm][fo][r];
        }
    }
  }
}

// ---------------- sum the 2 K-split partials -> NCHW fp32 out -------------
__global__ __launch_bounds__(256) void reduce_out(
    const float* __restrict__ part, float* __restrict__ out, int n)
{
  int i = (blockIdx.x * 256 + threadIdx.x) * 4;
  if (i < n) {
    f32x4 a = *(const f32x4*)(part + i);
    f32x4 b = *(const f32x4*)(part + n + i);
    *(f32x4*)(out + i) = a + b;
  }
}

extern "C" void kernel_launch(void* const* d_in, const int* in_sizes, int n_in,
                              void* d_out, int out_size, void* d_ws, size_t ws_size,
                              hipStream_t stream)
{
  const float* x    = (const float*)d_in[0];
  const float* w_p1 = (const float*)d_in[1];
  const float* b_p1 = (const float*)d_in[2];
  const float* w_m1 = (const float*)d_in[3];
  const float* b_m1 = (const float*)d_in[4];
  const float* w_c1 = (const float*)d_in[5];
  const float* w_p2 = (const float*)d_in[6];
  const float* b_p2 = (const float*)d_in[7];
  const float* w_m2 = (const float*)d_in[8];
  const float* b_m2 = (const float*)d_in[9];
  const float* w_c2 = (const float*)d_in[10];
  float* out = (float*)d_out;

  char* ws = (char*)d_ws;
  auto align_up = [](size_t v) { return (v + 255) & ~(size_t)255; };
  size_t off = 0;
  unsigned short* xclp = (unsigned short*)(ws + off); off += align_up((size_t)B * PPIX * C1 * 2);
  unsigned short* hclp = (unsigned short*)(ws + off); off += align_up((size_t)B * PPIX * HID * 2);
  float* pmpart = (float*)(ws + off); off += align_up((size_t)4 * M_TOT * 32 * 4);
  int4*   tabO = (int4*)(ws + off);   off += align_up((size_t)M_TOT * NK * 16);
  float4* tabG = (float4*)(ws + off); off += align_up((size_t)M_TOT * NK * 16);
  unsigned short* wr1 = (unsigned short*)(ws + off); off += align_up((size_t)HID * K1 * 2);
  unsigned short* wr2 = (unsigned short*)(ws + off); off += align_up((size_t)OUT2 * K2 * 2);
  unsigned short* wpr1 = (unsigned short*)(ws + off); off += align_up((size_t)32 * K1 * 2);
  unsigned short* wpr2 = (unsigned short*)(ws + off); off += align_up((size_t)32 * K2 * 2);
  float* outpart = (float*)(ws + off); off += align_up((size_t)2 * M_TOT * OUT2 * 4);
  unsigned short* Abuf = (unsigned short*)(ws + off);
  size_t avail = (ws_size > off) ? ws_size - off : 0;
  auto pick_nc = [&](size_t K) {
    const int cands[3] = {1, 7, 49};
    for (int i = 0; i < 3; ++i)
      if ((size_t)(M_TOT / cands[i]) * K * 2 <= avail) return cands[i];
    return 49;
  };
  int nc1 = pick_nc(K1), nc2 = pick_nc(K2);

  // zero pad rings (full-buffer zero; interiors overwritten below)
  zero_kernel<<<(int)((size_t)B * PPIX * C1 * 2 / 16 + 255) / 256, 256, 0, stream>>>(
      (u32x4*)xclp, (int)((size_t)B * PPIX * C1 * 2 / 16));
  zero_kernel<<<(int)((size_t)B * PPIX * HID * 2 / 16 + 255) / 256, 256, 0, stream>>>(
      (u32x4*)hclp, (int)((size_t)B * PPIX * HID * 2 / 16));

  // prep (weights + input transpose)
  xpose_kernel<<<dim3(25, C1 / 32, B), 256, 0, stream>>>(x, xclp, C1);
  wrep_kernel<<<HID, 256, 0, stream>>>(w_c1, wr1, C1);
  wrep_kernel<<<OUT2, 256, 0, stream>>>(w_c2, wr2, HID);
  wprep_kernel<<<32, 256, 0, stream>>>(w_p1, w_m1, wpr1, C1);
  wprep_kernel<<<32, 256, 0, stream>>>(w_p2, w_m2, wpr2, HID);

  // ---- layer 1 ----
  pconv_mfma<C1, 4><<<dim3(M_TOT / 128, 4), 256, 0, stream>>>(xclp, wpr1, pmpart);
  mktab_kernel<4><<<(M_TOT * NK + 255) / 256, 256, 0, stream>>>(pmpart, b_p1, b_m1, tabO, tabG);
  {
    int mc = M_TOT / nc1;
    for (int ci = 0; ci < nc1; ++ci) {
      int mb = ci * mc;
      sample_cl_kernel<<<mc / 4, 256, 0, stream>>>(xclp, tabO, tabG, Abuf, C1, mb);
      gemm_mfma<128, 0><<<dim3(mc / 128, HID / 128, 1), 256, 0, stream>>>(
          Abuf, wr1, hclp, K1, HID, mb, 1);
    }
  }
  // ---- layer 2 ----
  pconv_mfma<HID, 4><<<dim3(M_TOT / 128, 4), 256, 0, stream>>>(hclp, wpr2, pmpart);
  mktab_kernel<4><<<(M_TOT * NK + 255) / 256, 256, 0, stream>>>(pmpart, b_p2, b_m2, tabO, tabG);
  {
    int mc = M_TOT / nc2;
    for (int ci = 0; ci < nc2; ++ci) {
      int mb = ci * mc;
      sample_cl_kernel<<<mc / 4, 256, 0, stream>>>(hclp, tabO, tabG, Abuf, HID, mb);
      gemm_mfma<64, 1><<<dim3(mc / 128, OUT2 / 64, 2), 256, 0, stream>>>(
          Abuf, wr2, outpart, K2, OUT2, mb, 2);
    }
  }
  reduce_out<<<(M_TOT * OUT2 / 4 + 255) / 256, 256, 0, stream>>>(
      outpart, out, M_TOT * OUT2);
}